// Round 8
// baseline (87.892 us; speedup 1.0000x reference)
//
#include <hip/hip_runtime.h>
#include <math.h>

#define N_PTS   2048
#define BLOCK   256
#define NQ      8      // queries per thread -> 2048 queries per block
#define SLAB    128    // candidates walked per block (no staging -- just a range)
#define NSLAB   (N_PTS / SLAB)   // 16

// Grid: (32 bs, 2 dir, 16 slab) = 1024 blocks x 256 threads = 16 waves/CU.
//
// R8 experiment: ZERO LDS. Candidates are wave-uniform (all lanes use the
// same candidate j, j = loop counter), so they are read via uniform indexing
// -> clang uniformity analysis emits s_load into SGPRs (SMEM pipe), and the
// pair FMA takes the candidate coordinate as its one allowed SGPR operand.
// This deletes LDS staging, __syncthreads, all ds_read + lgkmcnt waits from
// the hot path -- the shared invariant of four structurally-null rounds
// (R0/R3/R6/R7 all ~81-84 us with min kernel ~33 us vs ~13 us VALU floor).
// |t|^2 is recomputed per candidate in VALU: +5 ops per 2 candidates, ~9%
// on top of 56 -- acceptable for removing the LDS pipe from the loop.
// R5 lesson kept: no aggregate arrays / pointer casts (scratch spill).
__global__ __launch_bounds__(BLOCK) void chamfer_min_kernel(
    const float* __restrict__ pred,
    const float* __restrict__ tgt,
    unsigned int* __restrict__ wsmin,
    float* __restrict__ out)
{
    const int bs   = blockIdx.x;   // 0..31
    const int dir  = blockIdx.y;   // 0..1
    const int slab = blockIdx.z;   // 0..15
    const int tid  = threadIdx.x;

    // Zero the output accumulator in-kernel (kernel boundary orders it before
    // the finalize kernel's atomicAdds) -- saves the 4 B memset dispatch.
    if (bs == 0 && dir == 0 && slab == 0 && tid == 0)
        atomicExch((unsigned int*)out, 0u);

    const float* Abase = (dir ? tgt : pred) + (size_t)bs * N_PTS * 3;  // queries
    const float* Bbase = (dir ? pred : tgt) + (size_t)bs * N_PTS * 3
                         + (size_t)slab * SLAB * 3;                    // candidates

    // 8 queries per thread, strided tid + 256k; pre-scale by -2 -> pure FMA.
    float nx[NQ], ny[NQ], nz[NQ], p2[NQ], best[NQ];
    #pragma unroll
    for (int k = 0; k < NQ; ++k) {
        const int q = tid + BLOCK * k;
        const float px = Abase[3 * q + 0];
        const float py = Abase[3 * q + 1];
        const float pz = Abase[3 * q + 2];
        nx[k] = -2.0f * px;
        ny[k] = -2.0f * py;
        nz[k] = -2.0f * pz;
        p2[k] = px * px + py * py + pz * pz;
        best[k] = 3.4e38f;
    }

    // Hot loop: candidates read through UNIFORM addresses (s_load, SMEM pipe).
    // 2 candidates/step; fminf(fminf(best,v0),v1) -> v_min3_f32.
    // Per 2-cand step per wave: ~6 uniform dwords + 5 VALU (|t|^2) + 56 VALU.
    #pragma unroll 4
    for (int j = 0; j < SLAB; j += 2) {
        const float x0 = Bbase[3 * j + 0];
        const float y0 = Bbase[3 * j + 1];
        const float z0 = Bbase[3 * j + 2];
        const float x1 = Bbase[3 * j + 3];
        const float y1 = Bbase[3 * j + 4];
        const float z1 = Bbase[3 * j + 5];
        const float w0 = x0 * x0 + y0 * y0 + z0 * z0;
        const float w1 = x1 * x1 + y1 * y1 + z1 * z1;
        #pragma unroll
        for (int k = 0; k < NQ; ++k) {
            const float v0 = fmaf(nx[k], x0,
                             fmaf(ny[k], y0,
                             fmaf(nz[k], z0, w0)));   // |t|^2 - 2 p.t
            const float v1 = fmaf(nx[k], x1,
                             fmaf(ny[k], y1,
                             fmaf(nz[k], z1, w1)));
            best[k] = fminf(fminf(best[k], v0), v1);
        }
    }

    // Combine partial mins across slabs via uint atomicMin (d2 clamped >= 0).
    // uint ordering == float ordering for non-negative floats.
    const int base = (dir * 32 + bs) * N_PTS;
    #pragma unroll
    for (int k = 0; k < NQ; ++k) {
        const float d2 = fmaxf(p2[k] + best[k], 0.0f);
        atomicMin(&wsmin[base + tid + BLOCK * k], __float_as_uint(d2));
    }
}

// 131072 min-d^2 values -> sqrt -> sum / 65536 -> out scalar.
// Grid: 128 blocks x 256 threads, exactly one float4 per thread.
__global__ __launch_bounds__(256) void chamfer_finalize_kernel(
    const float4* __restrict__ wsmin,
    float* __restrict__ out)
{
    __shared__ float red[256 / 64];
    const int i = blockIdx.x * 256 + threadIdx.x;
    const float4 t = wsmin[i];
    float s = sqrtf(t.x) + sqrtf(t.y) + sqrtf(t.z) + sqrtf(t.w);

    for (int off = 32; off > 0; off >>= 1)
        s += __shfl_down(s, off, 64);
    const int tid = threadIdx.x;
    if ((tid & 63) == 0) red[tid >> 6] = s;
    __syncthreads();
    if (tid == 0) {
        const float blk = red[0] + red[1] + red[2] + red[3];
        atomicAdd(out, blk * (1.0f / 65536.0f));  // 1/(B*S*N), N==M
    }
}

extern "C" void kernel_launch(void* const* d_in, const int* in_sizes, int n_in,
                              void* d_out, int out_size, void* d_ws, size_t ws_size,
                              hipStream_t stream) {
    const float* pred = (const float*)d_in[0];
    const float* tgt  = (const float*)d_in[1];
    float* out = (float*)d_out;
    unsigned int* wsmin = (unsigned int*)d_ws;   // 2*32*2048 = 131072 uints (512 KB)

    // Poison ws to +large (0x7F7F7F7F = 3.39e38f, uint-order-consistent).
    // (out is zeroed inside the min kernel -- one fewer dispatch.)
    hipMemsetAsync(wsmin, 0x7F, (size_t)131072 * sizeof(unsigned int), stream);

    dim3 grid(32, 2, NSLAB);
    chamfer_min_kernel<<<grid, BLOCK, 0, stream>>>(pred, tgt, wsmin, out);

    chamfer_finalize_kernel<<<131072 / (256 * 4), 256, 0, stream>>>(
        (const float4*)wsmin, out);
}